// Round 18
// baseline (90.805 us; speedup 1.0000x reference)
//
#include <hip/hip_runtime.h>

#define NQ 10
#define TS 10
#define DIM 1024
#define ND 1024

typedef _Float16 h4 __attribute__((ext_vector_type(4)));
typedef __fp16  p2 __attribute__((ext_vector_type(2)));   // cvt_pkrtz result type
typedef float f4 __attribute__((ext_vector_type(4)));

__device__ __forceinline__ f4 mfma16(h4 a, h4 b, f4 c) {
    return __builtin_amdgcn_mfma_f32_16x16x16f16(a, b, c, 0, 0, 0);
}
__device__ __forceinline__ h4 cvt_h4(f4 x) {
    p2 lo = __builtin_amdgcn_cvt_pkrtz(x[0], x[1]);
    p2 hi = __builtin_amdgcn_cvt_pkrtz(x[2], x[3]);
    h4 r; r[0] = lo[0]; r[1] = lo[1]; r[2] = hi[0]; r[3] = hi[1];
    return r;
}
__device__ __forceinline__ float hsel(int ob, int ib, float cq, float sq) {
    return (ob == ib) ? cq : (ob ? sq : -sq);
}
// Force a (possibly SGPR-resident uniform) value into a VGPR. Works around a
// gfx950 backend bug: V_ADD_F32 with two SGPR sources (constant-bus violation)
// emitted for wave-uniform float arithmetic (R16 compile failure).
__device__ __forceinline__ float vmov(float x) {
    float y;
    asm("v_mov_b32 %0, %1" : "=v"(y) : "v"(x));
    return y;
}

// TWO samples per wave (512 blocks): every latency hole in sample A's chain
// is filled by sample B's independent instructions — intra-wave ILP from
// problem parallelism (cross-wave TLP failed R1; single-sample pipelining
// exhausted R13-R15 at ~65% stall). All uniform inputs pass through vmov()
// so gate/diag arithmetic runs on VGPRs (constant-bus-safe).
__global__ __launch_bounds__(64, 1) void qsim_kernel(
    const float* __restrict__ re_in, const float* __restrict__ im_in,
    const float* __restrict__ phis, const float* __restrict__ gs,
    float* __restrict__ out)
{
    const int lane = threadIdx.x;
    const int quad = lane >> 4;
    const int cc = lane & 15;
    const int c3 = (cc >> 3) & 1, c2 = (cc >> 2) & 1, c1 = (cc >> 1) & 1, c0 = cc & 1;
    const int q1 = quad >> 1, q0 = quad & 1;

    const int smp[2] = {(int)blockIdx.x, (int)blockIdx.x + 512};
    const float* prp[2]; const float* pip[2]; const float* php[2];
#pragma unroll
    for (int u = 0; u < 2; ++u) {
        prp[u] = re_in + smp[u] * DIM;
        pip[u] = im_in + smp[u] * DIM;
        php[u] = phis + smp[u] * (3 * NQ * TS);
    }

    const int lbase = 256 * quad + cc;

    // ---- load both states into fragment layout ----
    f4 Sr[2][4], Si[2][4];
#pragma unroll
    for (int u = 0; u < 2; ++u)
#pragma unroll
        for (int n = 0; n < 4; ++n)
#pragma unroll
            for (int s = 0; s < 4; ++s) {
                Sr[u][n][s] = prp[u][lbase + 64 * s + 16 * n];
                Si[u][n][s] = pip[u][lbase + 64 * s + 16 * n];
            }

    const float inv = 0.15811388300841897f;  // 1/(2*sqrt(10))
    float gkv[2][TS];
#pragma unroll
    for (int u = 0; u < 2; ++u)
#pragma unroll
        for (int t = 0; t < TS; ++t)
            gkv[u][t] = -0.5f * (vmov(gs[smp[u] * TS + t]) * inv);

    // ---- normalize (per sample) ----
#pragma unroll
    for (int u = 0; u < 2; ++u) {
        float nrm = 0.f;
#pragma unroll
        for (int n = 0; n < 4; ++n)
#pragma unroll
            for (int s = 0; s < 4; ++s)
                nrm += Sr[u][n][s] * Sr[u][n][s] + Si[u][n][s] * Si[u][n][s];
#pragma unroll
        for (int off = 32; off >= 1; off >>= 1) nrm += __shfl_xor(nrm, off, 64);
        const float scl = rsqrtf(nrm);
#pragma unroll
        for (int n = 0; n < 4; ++n) { Sr[u][n] *= scl; Si[u][n] *= scl; }
    }

    // ---- static pairsum per element (lane-only; shared by both samples) ----
    float psv[4][4];
    const int pbase = __popc(quad) + __popc(cc);
#pragma unroll
    for (int n = 0; n < 4; ++n)
#pragma unroll
        for (int s = 0; s < 4; ++s) {
            const int p = pbase + __popc(n) + __popc(s);
            const int z = NQ - 2 * p;
            psv[n][s] = 0.5f * (float)(z * z - NQ);
        }
    const float fq1 = (float)q1, fq0 = (float)q0;
    const float fc3 = (float)c3, fc2 = (float)c2, fc1 = (float)c1, fc0 = (float)c0;

    float DCP[2][4][4], DSP[2][4][4];
    h4 gb[2]; h4 hb[2][4][4];
    float bcur[2][NQ];
    float pipe[2][30];

    auto make_trig = [&](const float* v, float kcur,
                         float (&dcp)[4][4], float (&dsp)[4][4]) {
        float sv = 0.f;
#pragma unroll
        for (int i = 0; i < NQ; ++i) sv += v[i];
        float base = fmaf(-0.5f, sv, 0.f);
        base = fmaf(fq1, v[0], base); base = fmaf(fq0, v[1], base);
        base = fmaf(fc3, v[6], base); base = fmaf(fc2, v[7], base);
        base = fmaf(fc1, v[8], base); base = fmaf(fc0, v[9], base);
        const float addS[4] = {0.f, v[3], v[2], v[2] + v[3]};
        const float addN[4] = {0.f, v[5], v[4], v[4] + v[5]};
#pragma unroll
        for (int n = 0; n < 4; ++n)
#pragma unroll
            for (int s = 0; s < 4; ++s) {
                const float phi = fmaf(kcur, psv[n][s], base + addN[n] + addS[s]);
                float sp, cp;
                __sincosf(phi, &sp, &cp);
                dcp[n][s] = cp;
                dsp[n][s] = sp;
            }
    };
    auto make_tiles = [&](const float* th_src, h4& gbo, h4 (&hbo)[4][4]) {
        float C[NQ], S[NQ];
#pragma unroll
        for (int g = 0; g < NQ; ++g) {
            float sg, cg;
            __sincosf(0.5f * th_src[g], &sg, &cg);
            S[g] = sg; C[g] = cg;
        }
        {
            const float f01 = hsel(c3, q1, C[0], S[0]) * hsel(c2, q0, C[1], S[1]);
            float e[4];
#pragma unroll
            for (int s = 0; s < 4; ++s)
                e[s] = f01 * hsel(c1, s >> 1, C[2], S[2]) * hsel(c0, s & 1, C[3], S[3]);
            p2 lo = __builtin_amdgcn_cvt_pkrtz(e[0], e[1]);
            p2 hi = __builtin_amdgcn_cvt_pkrtz(e[2], e[3]);
            gbo[0] = lo[0]; gbo[1] = lo[1]; gbo[2] = hi[0]; gbo[3] = hi[1];
        }
        const float F67 = hsel(c3, q1, C[6], S[6]) * hsel(c2, q0, C[7], S[7]);
        float F89[4];
#pragma unroll
        for (int s = 0; s < 4; ++s)
            F89[s] = F67 * hsel(c1, s >> 1, C[8], S[8]) * hsel(c0, s & 1, C[9], S[9]);
#pragma unroll
        for (int n = 0; n < 4; ++n)
#pragma unroll
            for (int j = 0; j < 4; ++j) {
                const float F45 = hsel(n >> 1, j >> 1, C[4], S[4])
                                * hsel(n & 1,  j & 1,  C[5], S[5]);
                p2 lo = __builtin_amdgcn_cvt_pkrtz(F45 * F89[0], F45 * F89[1]);
                p2 hi = __builtin_amdgcn_cvt_pkrtz(F45 * F89[2], F45 * F89[3]);
                hbo[n][j][0] = lo[0]; hbo[n][j][1] = lo[1];
                hbo[n][j][2] = hi[0]; hbo[n][j][3] = hi[1];
            }
    };

    // ---- prologue: step-0 prep for both samples ----
#pragma unroll
    for (int u = 0; u < 2; ++u) {
        float phs0[30];
#pragma unroll
        for (int j = 0; j < 30; ++j) phs0[j] = vmov(php[u][j]);
        make_trig(&phs0[0], 0.f, DCP[u], DSP[u]);   // v0 = a0 (b(-1)=0), k=0
        make_tiles(&phs0[10], gb[u], hb[u]);
#pragma unroll
        for (int i = 0; i < NQ; ++i) bcur[u][i] = phs0[20 + i];
    }

    const f4 zf4 = {0.f, 0.f, 0.f, 0.f};

    for (int tt = 0; tt < TS; ++tt) {
        // ---- 1. issue next-step phi loads (consumed after the MFMA block) ----
        if (tt + 1 < TS) {
#pragma unroll
            for (int u = 0; u < 2; ++u)
#pragma unroll
                for (int j = 0; j < 30; ++j)
                    pipe[u][j] = vmov(php[u][30 * (tt + 1) + j]);
        }

        // ---- 2. boundary diagonal (precomputed trig; pure FMA), both samples ----
#pragma unroll
        for (int u = 0; u < 2; ++u)
#pragma unroll
            for (int n = 0; n < 4; ++n)
#pragma unroll
                for (int s = 0; s < 4; ++s) {
                    const float cp = DCP[u][n][s], sp = DSP[u][n][s];
                    const float xr = Sr[u][n][s], xi = Si[u][n][s];
                    Sr[u][n][s] = cp * xr - sp * xi;
                    Si[u][n][s] = sp * xr + cp * xi;
                }

        // ---- 3. Ry block (stage G, stage H), both samples interleaved ----
        h4 ar[2][4], ai[2][4];
#pragma unroll
        for (int u = 0; u < 2; ++u)
#pragma unroll
            for (int n = 0; n < 4; ++n) {
                ar[u][n] = cvt_h4(Sr[u][n]);
                ai[u][n] = cvt_h4(Si[u][n]);
            }
        f4 Tr[2][4], Ti[2][4];
#pragma unroll
        for (int u = 0; u < 2; ++u)
#pragma unroll
            for (int n = 0; n < 4; ++n) {
                Tr[u][n] = mfma16(ar[u][n], gb[u], zf4);
                Ti[u][n] = mfma16(ai[u][n], gb[u], zf4);
            }
        h4 tr[2][4], ti[2][4];
#pragma unroll
        for (int u = 0; u < 2; ++u)
#pragma unroll
            for (int n = 0; n < 4; ++n) {
                tr[u][n] = cvt_h4(Tr[u][n]);
                ti[u][n] = cvt_h4(Ti[u][n]);
            }
#pragma unroll
        for (int u = 0; u < 2; ++u)
#pragma unroll
            for (int n = 0; n < 4; ++n) {
                f4 accr = zf4, acci = zf4;
#pragma unroll
                for (int j = 0; j < 4; ++j) {
                    accr = mfma16(tr[u][j], hb[u][n][j], accr);
                    acci = mfma16(ti[u][j], hb[u][n][j], acci);
                }
                Sr[u][n] = accr;
                Si[u][n] = acci;
            }

        // ---- 4. prep step tt+1 (overwrites DCP/DSP/gb/hb/bcur in place) ----
        if (tt + 1 < TS) {
#pragma unroll
            for (int u = 0; u < 2; ++u) {
                float vN[NQ];
#pragma unroll
                for (int i = 0; i < NQ; ++i) vN[i] = pipe[u][i] + bcur[u][i];
                make_trig(vN, gkv[u][tt], DCP[u], DSP[u]);
                make_tiles(&pipe[u][10], gb[u], hb[u]);
#pragma unroll
                for (int i = 0; i < NQ; ++i) bcur[u][i] = pipe[u][20 + i];
            }
        } else {
#pragma unroll
            for (int u = 0; u < 2; ++u)
                make_trig(bcur[u], gkv[u][TS - 1], DCP[u], DSP[u]);  // trailing
        }
    }

    // ---- trailing diagonal + store ----
#pragma unroll
    for (int u = 0; u < 2; ++u) {
        float* outr = out + smp[u] * DIM;
        float* outi = out + ND * DIM + smp[u] * DIM;
#pragma unroll
        for (int n = 0; n < 4; ++n)
#pragma unroll
            for (int s = 0; s < 4; ++s) {
                const float cp = DCP[u][n][s], sp = DSP[u][n][s];
                const float xr = Sr[u][n][s], xi = Si[u][n][s];
                outr[lbase + 64 * s + 16 * n] = cp * xr - sp * xi;
                outi[lbase + 64 * s + 16 * n] = sp * xr + cp * xi;
            }
    }
}

extern "C" void kernel_launch(void* const* d_in, const int* in_sizes, int n_in,
                              void* d_out, int out_size, void* d_ws, size_t ws_size,
                              hipStream_t stream) {
    const float* re_in = (const float*)d_in[0];
    const float* im_in = (const float*)d_in[1];
    const float* phis  = (const float*)d_in[2];
    const float* gs    = (const float*)d_in[3];
    float* out = (float*)d_out;
    qsim_kernel<<<ND / 2, 64, 0, stream>>>(re_in, im_in, phis, gs, out);
}